// Round 6
// baseline (69.996 us; speedup 1.0000x reference)
//
#include <hip/hip_runtime.h>
#include <hip/hip_bf16.h>

#define B_ 128
#define I_ 2048
#define O_ 2048
#define SEG 10
#define BK 32
#define KSLICE 1024
#define NST (KSLICE / BK)   // 32 k-steps per wave (half of K)
#define XTILE 8192          // x tile: 128 rows x 32 k x 2B bf16, swizzled
#define DCH 1280            // D chunk: 32 i x 10 j x 4B f32 (contiguous)
#define DLS 1536            // slot stride: 1280 D + 128 w + pad

typedef __attribute__((ext_vector_type(8))) short bf16x8;
typedef __attribute__((ext_vector_type(4))) float f32x4;

static __device__ __forceinline__ unsigned short f2bf(float f) {
    unsigned u = __float_as_uint(f);
    u += 0x7FFFu + ((u >> 16) & 1u);
    return (unsigned short)(u >> 16);
}

#define GLDS16(SRC, DST) \
    __builtin_amdgcn_global_load_lds( \
        (const __attribute__((address_space(1))) unsigned*)(SRC), \
        (__attribute__((address_space(3))) unsigned*)(DST), 16, 0, 0)
#define GLDS4(SRC, DST) \
    __builtin_amdgcn_global_load_lds( \
        (const __attribute__((address_space(1))) unsigned*)(SRC), \
        (__attribute__((address_space(3))) unsigned*)(DST), 4, 0, 0)

#define WAITVM(N) asm volatile("s_waitcnt vmcnt(" #N ")" ::: "memory")
#define BARRIER() do { __builtin_amdgcn_sched_barrier(0); \
                       __builtin_amdgcn_s_barrier(); \
                       __builtin_amdgcn_sched_barrier(0); } while (0)

// ---------------------------------------------------------------------------
// Prepass: x [128][2048] f32 -> xb: 64 tiles of [128 rows][32 k] bf16.
// Row stride 64 B; XOR swizzle: byte(row,kl) = row*64 + ((kl*2) ^ sw2(row)),
// sw2(row) = ((row>>1)&3)<<4.
// ---------------------------------------------------------------------------
__global__ void xconv(const float* __restrict__ x, char* __restrict__ xb) {
    int idx = blockIdx.x * 256 + threadIdx.x;   // 0..32767, one 8-k chunk each
    int row = idx >> 8;                         // 0..127
    int c   = idx & 255;
    int k0  = c * 8;
    int tt  = k0 >> 5;                          // global tile 0..63
    int kl  = k0 & 31;

    const float* xp = x + (size_t)row * I_ + k0;
    float4 a = *reinterpret_cast<const float4*>(xp);
    float4 b = *reinterpret_cast<const float4*>(xp + 4);

    bf16x8 h;
    h[0] = (short)f2bf(a.x); h[1] = (short)f2bf(a.y);
    h[2] = (short)f2bf(a.z); h[3] = (short)f2bf(a.w);
    h[4] = (short)f2bf(b.x); h[5] = (short)f2bf(b.y);
    h[6] = (short)f2bf(b.z); h[7] = (short)f2bf(b.w);

    int sw = ((row >> 1) & 3) << 4;
    size_t off = (size_t)tt * XTILE + row * 64 + ((kl * 2) ^ sw);
    *reinterpret_cast<bf16x8*>(xb + off) = h;
}

// ---------------------------------------------------------------------------
// Main kernel: grid 1024, 4 waves/block (50 KB LDS -> 3 blocks/CU, 12
// waves/CU in 3 independent barrier domains). wave = (p = o, s = K-half):
// block covers o0,o0+1 x both K-halves. 1 o per wave, BK=32.
// x double-buffered (shared by the two same-slice waves), D/w triple-buffered
// wave-private. Uniform WAITVM(7); stages issued only after the post-compute
// barrier. Split-K combine via LDS before the relu epilogue.
// ---------------------------------------------------------------------------
__global__ __launch_bounds__(256, 3) void neuro_fused(
    const char*  __restrict__ xb,     // swizzled bf16 x tiles
    const float* __restrict__ ctx,    // [O_]
    const float* __restrict__ w,      // [O_, I_]
    const float* __restrict__ bias,   // [O_]
    const float* __restrict__ astro,  // [O_]
    const float* __restrict__ D,      // [O_, I_, SEG]
    float* __restrict__ out)          // [B_, O_]
{
    __shared__ __align__(16) char xs[2][2][XTILE];   // [slice][buf] 32 KiB
    __shared__ __align__(16) char dls[4][3][DLS];    // [wave][slot] 18 KiB

    const int tid  = threadIdx.x;
    const int wave = tid >> 6;
    const int lane = tid & 63;
    const int p    = wave >> 1;   // o within block
    const int s    = wave & 1;    // k-slice
    const int o    = blockIdx.x * 2 + p;
    const int col  = lane & 15;   // MFMA n-index
    const int g    = lane >> 4;   // k-group

    f32x4 acc[8];
#pragma unroll
    for (int m = 0; m < 8; ++m) acc[m] = (f32x4){0.f, 0.f, 0.f, 0.f};

    // scalar epilogue params (SMEM loads -> lgkmcnt, no vmcnt pollution)
    float am = astro[o] * ctx[o];
    am = 1.0f / (1.0f + __expf(-am));
    const float bo = bias[o];

    // per-lane B-fragment addressing: cols 0..9 dendrite, 10..15 weight row
    // (cols 11..15 compute the same finite dot as col 10; epilogue ignores them)
    const int fbase = (col < 10) ? col * 4 : DCH;
    const int fstr  = (col < 10) ? 40 : 4;
    const int sw    = ((col >> 1) & 3) << 4;

    // 4 DMA: the two same-slice waves each stage half the 8 KB tile
    auto stage_x = [&](int t, int buf) {
        const char* src = xb + (size_t)(s * NST + t) * XTILE + p * 4096 + lane * 16;
        char* dst = &xs[s][buf][p * 4096];
#pragma unroll
        for (int c = 0; c < 4; ++c)
            GLDS16(src + c * 1024, dst + c * 1024);
    };

    // 3 DMA: 1280 B D chunk + 128 B w chunk, wave-private
    auto stage_d = [&](int t, int slot) {
        const size_t krow = (size_t)(s * KSLICE + t * BK);
        const char* srcD = (const char*)D + ((size_t)o * (I_ * SEG) + krow * SEG) * 4;
        char* dst = &dls[wave][slot][0];
        GLDS16(srcD + lane * 16, dst);
        GLDS4(srcD + 1024 + lane * 4, dst + 1024);
        const char* srcW = (const char*)w + ((size_t)o * I_ + krow) * 4;
        if (lane < 32) GLDS4(srcW + lane * 4, dst + DCH);
    };

    auto compute = [&](int bufx, int slot) {
        const char* xbase = &xs[s][bufx][0];
        const char* dbase = &dls[wave][slot][0];
        bf16x8 af[8];
#pragma unroll
        for (int m = 0; m < 8; ++m)
            af[m] = *reinterpret_cast<const bf16x8*>(
                xbase + (m * 16 + col) * 64 + ((16 * g) ^ sw));
        const char* fp = dbase + fbase + (8 * g) * fstr;
        bf16x8 bfrag;
#pragma unroll
        for (int e = 0; e < 8; ++e) {
            float v = *reinterpret_cast<const float*>(fp + e * fstr);
            __hip_bfloat16 h = __float2bfloat16(v);
            bfrag[e] = *reinterpret_cast<short*>(&h);
        }
#pragma unroll
        for (int m = 0; m < 8; ++m)
            acc[m] = __builtin_amdgcn_mfma_f32_16x16x32_bf16(af[m], bfrag, acc[m], 0, 0, 0);
    };

    // prologue: [x(0),D(0)], [x(1),D(1)]  (oldest -> newest, 14 VMEM ops)
    stage_x(0, 0); stage_d(0, 0);
    stage_x(1, 1); stage_d(1, 1);

    int cslot = 0;   // t % 3
#pragma unroll 1
    for (int t = 0; t < NST; ++t) {
        // steady state: ops newer than [x(t),D(t)] are [x(t+1),D(t+1)] = 7
        if (t < NST - 1) { WAITVM(7); } else { WAITVM(0); }
        BARRIER();                 // x(t) visible to both same-slice waves
        compute(t & 1, cslot);
        BARRIER();                 // all readers done with xs[s][t&1]
        if (t + 2 < NST) {
            stage_x(t + 2, t & 1);                     // (t+2)&1 == t&1
            stage_d(t + 2, cslot == 0 ? 2 : cslot - 1); // (t+2)%3
        }
        cslot = (cslot == 2) ? 0 : cslot + 1;
    }

    // --- split-K combine through LDS (before relu!) --------------------------
    __syncthreads();   // loop done everywhere; reuse xs as scratch
    float* cs = reinterpret_cast<float*>(&xs[0][0][0]);
    if (s == 1) {
#pragma unroll
        for (int m = 0; m < 8; ++m)
            *reinterpret_cast<f32x4*>(cs + p * 2048 + m * 256 + lane * 4) = acc[m];
    }
    __syncthreads();
    if (s == 0) {
#pragma unroll
        for (int m = 0; m < 8; ++m) {
            f32x4 other = *reinterpret_cast<const f32x4*>(cs + p * 2048 + m * 256 + lane * 4);
#pragma unroll
            for (int r = 0; r < 4; ++r) {
                float v = acc[m][r] + other[r];
                float dend = (col < 10) ? fmaxf(v, 0.0f) : 0.0f;
#pragma unroll
                for (int sh = 1; sh < 16; sh <<= 1)
                    dend += __shfl_xor(dend, sh, 64);
                float lin = __shfl(v, (lane & 48) | 10, 64);
                if (col == 0) {
                    int b = m * 16 + g * 4 + r;
                    out[(size_t)b * O_ + o] = dend + am * lin + bo;
                }
            }
        }
    }
}

extern "C" void kernel_launch(void* const* d_in, const int* in_sizes, int n_in,
                              void* d_out, int out_size, void* d_ws, size_t ws_size,
                              hipStream_t stream) {
    const float* x     = (const float*)d_in[0];
    const float* ctx   = (const float*)d_in[1];
    // d_in[2] = prev_activation (unused by the reference output)
    const float* w     = (const float*)d_in[3];
    const float* bias  = (const float*)d_in[4];
    const float* astro = (const float*)d_in[5];
    const float* D     = (const float*)d_in[6];
    float* out = (float*)d_out;
    char* xb = (char*)d_ws;   // 512 KiB swizzled bf16 x

    xconv<<<dim3(128), dim3(256), 0, stream>>>(x, xb);
    neuro_fused<<<dim3(1024), dim3(256), 0, stream>>>(xb, ctx, w, bias, astro, D, out);
}

// Round 7
// 66.935 us; speedup vs baseline: 1.0457x; 1.0457x over previous
//
#include <hip/hip_runtime.h>
#include <hip/hip_bf16.h>

#define B_ 128
#define I_ 2048
#define O_ 2048
#define SEG 10
#define BK 32
#define NT (I_ / BK)       // 64 k-steps, full K per wave
#define XTILE 8192         // x tile: 128 rows x 32 k x 2B bf16, row-major
#define DCH 1280           // D chunk: 32 i x 10 j x 4B f32 (contiguous)
#define DLS 1536           // slot stride: 1280 D + 128 w + pad

typedef __attribute__((ext_vector_type(8))) short bf16x8;
typedef __attribute__((ext_vector_type(4))) float f32x4;

static __device__ __forceinline__ unsigned short f2bf(float f) {
    unsigned u = __float_as_uint(f);
    u += 0x7FFFu + ((u >> 16) & 1u);
    return (unsigned short)(u >> 16);
}

#define GLDS16(SRC, DST) \
    __builtin_amdgcn_global_load_lds( \
        (const __attribute__((address_space(1))) unsigned*)(SRC), \
        (__attribute__((address_space(3))) unsigned*)(DST), 16, 0, 0)
#define GLDS4(SRC, DST) \
    __builtin_amdgcn_global_load_lds( \
        (const __attribute__((address_space(1))) unsigned*)(SRC), \
        (__attribute__((address_space(3))) unsigned*)(DST), 4, 0, 0)

#define WAITVM(N) asm volatile("s_waitcnt vmcnt(" #N ")" ::: "memory")
#define SB() __builtin_amdgcn_sched_barrier(0)

// ---------------------------------------------------------------------------
// Prepass: x [128][2048] f32 -> xb: 64 tiles of [128 rows][32 k] bf16,
// plain row-major (no swizzle — A-frags are read from L2, not LDS).
// byte(t,row,kl) = t*8192 + row*64 + kl*2
// ---------------------------------------------------------------------------
__global__ void xconv(const float* __restrict__ x, char* __restrict__ xb) {
    int idx = blockIdx.x * 256 + threadIdx.x;   // 0..32767, one 8-k chunk each
    int row = idx >> 8;                         // 0..127
    int c   = idx & 255;
    int k0  = c * 8;
    int tt  = k0 >> 5;                          // tile 0..63
    int kl  = k0 & 31;

    const float* xp = x + (size_t)row * I_ + k0;
    float4 a = *reinterpret_cast<const float4*>(xp);
    float4 b = *reinterpret_cast<const float4*>(xp + 4);

    bf16x8 h;
    h[0] = (short)f2bf(a.x); h[1] = (short)f2bf(a.y);
    h[2] = (short)f2bf(a.z); h[3] = (short)f2bf(a.w);
    h[4] = (short)f2bf(b.x); h[5] = (short)f2bf(b.y);
    h[6] = (short)f2bf(b.z); h[7] = (short)f2bf(b.w);

    size_t off = (size_t)tt * XTILE + row * 64 + kl * 2;
    *reinterpret_cast<bf16x8*>(xb + off) = h;
}

// ---------------------------------------------------------------------------
// Main kernel: 1024 single-wave blocks (64 thr), 2 o's per wave, full K.
// ZERO barriers. A-frags loaded straight from L2-resident xb into registers
// (1-step prefetch, double reg buffer). D+w staged wave-private via
// global_load_lds into a 4-slot LDS ring (3-step prefetch). Per-wave counted
// vmcnt paces the pipeline: per step issue [A(t+1): 8 ops][D(t+3): 6 ops];
// steady wait vmcnt(6) = A(t) landed, D(t) landed 3 steps ago.
// Slots (t, t+1, t+2, t+3) mod 4 = read / landed / landing / issuing.
// ---------------------------------------------------------------------------
__global__ __launch_bounds__(64) void neuro_fused(
    const char*  __restrict__ xb,     // bf16 x tiles
    const float* __restrict__ ctx,    // [O_]
    const float* __restrict__ w,      // [O_, I_]
    const float* __restrict__ bias,   // [O_]
    const float* __restrict__ astro,  // [O_]
    const float* __restrict__ D,      // [O_, I_, SEG]
    float* __restrict__ out)          // [B_, O_]
{
    __shared__ __align__(16) char dls[4][2][DLS];   // [slot][oo]  12.3 KiB

    const int lane = threadIdx.x & 63;
    const int o0   = blockIdx.x * 2;
    const int col  = lane & 15;   // MFMA n-index
    const int g    = lane >> 4;   // k-group

    f32x4 acc[2][8];
#pragma unroll
    for (int oo = 0; oo < 2; ++oo)
#pragma unroll
        for (int m = 0; m < 8; ++m) acc[oo][m] = (f32x4){0.f, 0.f, 0.f, 0.f};

    // per-lane B-fragment addressing: cols 0..9 dendrite (stride 40 B),
    // cols 10..15 weight row (epilogue only uses col 10)
    const int fbase = (col < 10) ? col * 4 : DCH;
    const int fstr  = (col < 10) ? 40 : 4;
    const int aoff  = col * 64 + g * 16;   // per-lane A offset within a tile

    // A(t): 8 x global_load_dwordx4, each m a contiguous coalesced 1 KB block
    auto issueA = [&](int t, bf16x8 (&dst)[8]) {
        const char* src = xb + (size_t)t * XTILE + aoff;
#pragma unroll
        for (int m = 0; m < 8; ++m)
            dst[m] = *reinterpret_cast<const bf16x8*>(src + m * 1024);
    };

    // D(t)+w(t) for both o's -> slot t&3  (6 vmcnt ops)
    auto issueD = [&](int t) {
        const size_t krow = (size_t)t * BK;
#pragma unroll
        for (int oo = 0; oo < 2; ++oo) {
            const char* srcD = (const char*)D + ((size_t)(o0 + oo) * (I_ * SEG) + krow * SEG) * 4;
            char* dst = &dls[t & 3][oo][0];
            GLDS16(srcD + lane * 16, dst);
            GLDS4(srcD + 1024 + lane * 4, dst + 1024);
            const char* srcW = (const char*)w + ((size_t)(o0 + oo) * I_ + krow) * 4;
            if (lane < 32) GLDS4(srcW + lane * 4, dst + DCH);
        }
    };

    auto compute = [&](int t, bf16x8 (&cur)[8]) {
#pragma unroll
        for (int oo = 0; oo < 2; ++oo) {
            const char* fp = &dls[t & 3][oo][0] + fbase + (8 * g) * fstr;
            bf16x8 bfrag;
#pragma unroll
            for (int e = 0; e < 8; ++e) {
                float v = *reinterpret_cast<const float*>(fp + e * fstr);
                bfrag[e] = (short)f2bf(v);
            }
#pragma unroll
            for (int m = 0; m < 8; ++m)
                acc[oo][m] = __builtin_amdgcn_mfma_f32_16x16x32_bf16(cur[m], bfrag, acc[oo][m], 0, 0, 0);
        }
    };

    auto STEP = [&](int t, bf16x8 (&cur)[8], bf16x8 (&nxt)[8]) {
        // FIFO at entry (newest->oldest): D(t+2)[6] | A(t)[8] | D(t+1)... done
        if (t == 0)      { WAITVM(12); }   // prologue: A(0) then D(0),D(1),D(2)
        else if (t < 61) { WAITVM(6);  }   // A(t) landed, D(t+2) may fly
        else             { WAITVM(0);  }   // tail: issue pattern broken, drain
        SB();
        compute(t, cur);
        SB();
        if (t < 63) issueA(t + 1, nxt);
        SB();
        if (t <= 60) issueD(t + 3);
        SB();
    };

    bf16x8 afA[8], afB[8];
    issueA(0, afA);
    issueD(0); issueD(1); issueD(2);

#pragma unroll 1
    for (int t = 0; t < NT; t += 2) {
        STEP(t,     afA, afB);
        STEP(t + 1, afB, afA);
    }

    // --- epilogue (scalar params loaded only now: no vmcnt pollution) -------
#pragma unroll
    for (int oo = 0; oo < 2; ++oo) {
        const int o = o0 + oo;
        float am = astro[o] * ctx[o];
        am = 1.0f / (1.0f + __expf(-am));
        const float bo = bias[o];
#pragma unroll
        for (int m = 0; m < 8; ++m) {
#pragma unroll
            for (int r = 0; r < 4; ++r) {
                float v = acc[oo][m][r];
                float dend = (col < 10) ? fmaxf(v, 0.0f) : 0.0f;
#pragma unroll
                for (int sh = 1; sh < 16; sh <<= 1)
                    dend += __shfl_xor(dend, sh, 64);
                float lin = __shfl(v, (lane & 48) | 10, 64);
                if (col == 0) {
                    int b = m * 16 + g * 4 + r;
                    out[(size_t)b * O_ + o] = dend + am * lin + bo;
                }
            }
        }
    }
}

extern "C" void kernel_launch(void* const* d_in, const int* in_sizes, int n_in,
                              void* d_out, int out_size, void* d_ws, size_t ws_size,
                              hipStream_t stream) {
    const float* x     = (const float*)d_in[0];
    const float* ctx   = (const float*)d_in[1];
    // d_in[2] = prev_activation (unused by the reference output)
    const float* w     = (const float*)d_in[3];
    const float* bias  = (const float*)d_in[4];
    const float* astro = (const float*)d_in[5];
    const float* D     = (const float*)d_in[6];
    float* out = (float*)d_out;
    char* xb = (char*)d_ws;   // 512 KiB bf16 x tiles

    xconv<<<dim3(128), dim3(256), 0, stream>>>(x, xb);
    neuro_fused<<<dim3(1024), dim3(64), 0, stream>>>(xb, ctx, w, bias, astro, D, out);
}

// Round 8
// 63.994 us; speedup vs baseline: 1.0938x; 1.0460x over previous
//
#include <hip/hip_runtime.h>
#include <hip/hip_bf16.h>

#define B_ 128
#define I_ 2048
#define O_ 2048
#define SEG 10
#define BK 32
#define KSLICE 1024
#define NST (KSLICE / BK)  // 32 k-steps per wave (half of K)
#define XTILE 8192         // x tile: 128 rows x 32 k x 2B bf16, row-major
#define DCH 1280           // D chunk: 32 i x 10 j x 4B f32 (contiguous)
#define DLS 1536           // per-o slot: 1280 D + 128 w + pad

typedef __attribute__((ext_vector_type(8))) short bf16x8;
typedef __attribute__((ext_vector_type(4))) float f32x4;

static __device__ __forceinline__ unsigned short f2bf(float f) {
    unsigned u = __float_as_uint(f);
    u += 0x7FFFu + ((u >> 16) & 1u);
    return (unsigned short)(u >> 16);
}

#define GLDS16(SRC, DST) \
    __builtin_amdgcn_global_load_lds( \
        (const __attribute__((address_space(1))) unsigned*)(SRC), \
        (__attribute__((address_space(3))) unsigned*)(DST), 16, 0, 0)
#define GLDS4(SRC, DST) \
    __builtin_amdgcn_global_load_lds( \
        (const __attribute__((address_space(1))) unsigned*)(SRC), \
        (__attribute__((address_space(3))) unsigned*)(DST), 4, 0, 0)

#define WAITVM(N) asm volatile("s_waitcnt vmcnt(" #N ")" ::: "memory")
#define SB() __builtin_amdgcn_sched_barrier(0)

// ---------------------------------------------------------------------------
// Prepass: x [128][2048] f32 -> xb: 64 tiles of [128 rows][32 k] bf16,
// row-major. byte(t,row,kl) = t*8192 + row*64 + kl*2
// ---------------------------------------------------------------------------
__global__ void xconv(const float* __restrict__ x, char* __restrict__ xb) {
    int idx = blockIdx.x * 256 + threadIdx.x;   // one 8-k chunk each
    int row = idx >> 8;
    int c   = idx & 255;
    int k0  = c * 8;
    int tt  = k0 >> 5;
    int kl  = k0 & 31;

    const float* xp = x + (size_t)row * I_ + k0;
    float4 a = *reinterpret_cast<const float4*>(xp);
    float4 b = *reinterpret_cast<const float4*>(xp + 4);

    bf16x8 h;
    h[0] = (short)f2bf(a.x); h[1] = (short)f2bf(a.y);
    h[2] = (short)f2bf(a.z); h[3] = (short)f2bf(a.w);
    h[4] = (short)f2bf(b.x); h[5] = (short)f2bf(b.y);
    h[6] = (short)f2bf(b.z); h[7] = (short)f2bf(b.w);

    size_t off = (size_t)tt * XTILE + row * 64 + kl * 2;
    *reinterpret_cast<bf16x8*>(xb + off) = h;
}

// ---------------------------------------------------------------------------
// Main kernel: 1024 blocks x 256 thr (4 waves) = 4 blocks/CU, 16 waves/CU,
// ALL self-paced (zero main-loop barriers). wave = (h = b-half, s = K-half)
// for the block's o-pair. Each wave: 2 o's, 64 b-rows (m=4), K = s*1024..+1023.
// A-frags from L2-resident xb into regs (1-step prefetch, double buffer,
// shared across both o's). D+w wave-private via global_load_lds, 3-slot ring
// (2-step prefetch). Steady pacing: wait vmcnt(6) = A(t),D(t) landed while
// D(t+1) flies; issue A(t+1) then D(t+2) after compute.
// Split-K combine via one __syncthreads + LDS at the end.
// ---------------------------------------------------------------------------
__global__ __launch_bounds__(256, 4) void neuro_fused(
    const char*  __restrict__ xb,     // bf16 x tiles
    const float* __restrict__ ctx,    // [O_]
    const float* __restrict__ w,      // [O_, I_]
    const float* __restrict__ bias,   // [O_]
    const float* __restrict__ astro,  // [O_]
    const float* __restrict__ D,      // [O_, I_, SEG]
    float* __restrict__ out)          // [B_, O_]
{
    __shared__ __align__(16) char dls[4][3][2][DLS];   // [wave][slot][oo] 36.9 KiB

    const int tid  = threadIdx.x;
    const int wave = tid >> 6;
    const int lane = tid & 63;
    const int s    = wave & 1;    // k-slice
    const int h    = wave >> 1;   // b-half
    const int o0   = blockIdx.x * 2;
    const int col  = lane & 15;   // MFMA n-index
    const int g    = lane >> 4;   // k-group

    f32x4 acc[2][4];
#pragma unroll
    for (int oo = 0; oo < 2; ++oo)
#pragma unroll
        for (int m = 0; m < 4; ++m) acc[oo][m] = (f32x4){0.f, 0.f, 0.f, 0.f};

    // per-lane B-fragment addressing: cols 0..9 dendrite (stride 40 B),
    // cols 10..15 read the weight row (epilogue uses only col 10)
    const int fbase = (col < 10) ? col * 4 : DCH;
    const int fstr  = (col < 10) ? 40 : 4;
    // per-lane A offset inside a tile: row = h*64 + m*16 + col
    const int aoff  = (h * 64 + col) * 64 + g * 16;

    // A(t): 4 x b128 from L2 (each m covers a contiguous aligned 1 KB)
    auto issueA = [&](int t, bf16x8 (&dst)[4]) {
        const char* src = xb + (size_t)(s * NST + t) * XTILE + aoff;
#pragma unroll
        for (int m = 0; m < 4; ++m)
            dst[m] = *reinterpret_cast<const bf16x8*>(src + m * 1024);
    };

    // D(t)+w(t) for both o's -> ring slot t%3  (6 vmcnt ops)
    auto issueD = [&](int t) {
        const size_t krow = (size_t)(s * KSLICE + t * BK);
        const int slot = t % 3;
#pragma unroll
        for (int oo = 0; oo < 2; ++oo) {
            const char* srcD = (const char*)D + ((size_t)(o0 + oo) * (I_ * SEG) + krow * SEG) * 4;
            char* dst = &dls[wave][slot][oo][0];
            GLDS16(srcD + lane * 16, dst);
            GLDS4(srcD + 1024 + lane * 4, dst + 1024);
            const char* srcW = (const char*)w + ((size_t)(o0 + oo) * I_ + krow) * 4;
            if (lane < 32) GLDS4(srcW + lane * 4, dst + DCH);
        }
    };

    auto compute = [&](int t, bf16x8 (&cur)[4]) {
        const int slot = t % 3;
#pragma unroll
        for (int oo = 0; oo < 2; ++oo) {
            const char* fp = &dls[wave][slot][oo][0] + fbase + (8 * g) * fstr;
            bf16x8 bfrag;
#pragma unroll
            for (int e = 0; e < 8; ++e) {
                float v = *reinterpret_cast<const float*>(fp + e * fstr);
                bfrag[e] = (short)f2bf(v);
            }
#pragma unroll
            for (int m = 0; m < 4; ++m)
                acc[oo][m] = __builtin_amdgcn_mfma_f32_16x16x32_bf16(cur[m], bfrag, acc[oo][m], 0, 0, 0);
        }
    };

    auto STEP = [&](int t, bf16x8 (&cur)[4], bf16x8 (&nxt)[4]) {
        // FIFO at entry (oldest->newest): A(t)[4], D(t+1)[6]; D(t) landed earlier
        if (t < NST - 1) { WAITVM(6); } else { WAITVM(0); }
        SB();
        compute(t, cur);
        SB();
        if (t + 1 < NST) issueA(t + 1, nxt);
        SB();
        if (t + 2 < NST) issueD(t + 2);
        SB();
    };

    bf16x8 afA[4], afB[4];
    issueA(0, afA);
    issueD(0); issueD(1);

#pragma unroll 1
    for (int t = 0; t < NST; t += 2) {
        STEP(t,     afA, afB);
        STEP(t + 1, afB, afA);
    }

    // --- split-K combine through LDS (before relu!) --------------------------
    __syncthreads();
    float* cs = reinterpret_cast<float*>(&dls[0][0][0][0]);   // >=16 KB scratch
    if (s == 1) {
#pragma unroll
        for (int oo = 0; oo < 2; ++oo)
#pragma unroll
            for (int m = 0; m < 4; ++m)
                *reinterpret_cast<f32x4*>(cs + ((h * 2 + oo) * 4 + m) * 256 + lane * 4) = acc[oo][m];
    }
    __syncthreads();
    if (s == 0) {
#pragma unroll
        for (int oo = 0; oo < 2; ++oo) {
            const int o = o0 + oo;
            float am = astro[o] * ctx[o];
            am = 1.0f / (1.0f + __expf(-am));
            const float bo = bias[o];
#pragma unroll
            for (int m = 0; m < 4; ++m) {
                f32x4 other = *reinterpret_cast<const f32x4*>(cs + ((h * 2 + oo) * 4 + m) * 256 + lane * 4);
#pragma unroll
                for (int r = 0; r < 4; ++r) {
                    float v = acc[oo][m][r] + other[r];
                    float dend = (col < 10) ? fmaxf(v, 0.0f) : 0.0f;
#pragma unroll
                    for (int sh = 1; sh < 16; sh <<= 1)
                        dend += __shfl_xor(dend, sh, 64);
                    float lin = __shfl(v, (lane & 48) | 10, 64);
                    if (col == 0) {
                        int b = h * 64 + m * 16 + g * 4 + r;
                        out[(size_t)b * O_ + o] = dend + am * lin + bo;
                    }
                }
            }
        }
    }
}

extern "C" void kernel_launch(void* const* d_in, const int* in_sizes, int n_in,
                              void* d_out, int out_size, void* d_ws, size_t ws_size,
                              hipStream_t stream) {
    const float* x     = (const float*)d_in[0];
    const float* ctx   = (const float*)d_in[1];
    // d_in[2] = prev_activation (unused by the reference output)
    const float* w     = (const float*)d_in[3];
    const float* bias  = (const float*)d_in[4];
    const float* astro = (const float*)d_in[5];
    const float* D     = (const float*)d_in[6];
    float* out = (float*)d_out;
    char* xb = (char*)d_ws;   // 512 KiB bf16 x tiles

    xconv<<<dim3(128), dim3(256), 0, stream>>>(x, xb);
    neuro_fused<<<dim3(1024), dim3(256), 0, stream>>>(xb, ctx, w, bias, astro, D, out);
}

// Round 9
// 63.570 us; speedup vs baseline: 1.1011x; 1.0067x over previous
//
#include <hip/hip_runtime.h>
#include <hip/hip_bf16.h>

#define B_ 128
#define I_ 2048
#define O_ 2048
#define SEG 10
#define BK 64
#define NT (I_ / BK)       // 32 k-steps
#define NSS (I_ / 128)     // 16 D-supersteps
#define XTILE 16384        // x tile: 128 rows x 64 k x 2B bf16, swizzled
#define DSS 5120           // D bytes per superstep per o (128 k x 10 j x 4B)

typedef __attribute__((ext_vector_type(8))) short bf16x8;
typedef __attribute__((ext_vector_type(4))) float f32x4;

static __device__ __forceinline__ unsigned short f2bf(float f) {
    unsigned u = __float_as_uint(f);
    u += 0x7FFFu + ((u >> 16) & 1u);
    return (unsigned short)(u >> 16);
}

#define GLDS16(SRC, DST) \
    __builtin_amdgcn_global_load_lds( \
        (const __attribute__((address_space(1))) unsigned*)(SRC), \
        (__attribute__((address_space(3))) unsigned*)(DST), 16, 0, 0)

// ---------------------------------------------------------------------------
// Prepass 1: x [128][2048] f32 -> xb: 32 tiles of [128 rows][64 k] bf16.
// Row stride 128 B; XOR swizzle: byte(row,kl) = row*128 + ((kl*2)^((row&7)<<4))
// ---------------------------------------------------------------------------
__global__ void xconv(const float* __restrict__ x, char* __restrict__ xb) {
    int idx = blockIdx.x * 256 + threadIdx.x;   // one 8-k chunk each
    int row = idx >> 8;
    int c   = idx & 255;
    int k0  = c * 8;
    int tt  = k0 >> 6;                          // tile 0..31
    int kl  = k0 & 63;

    const float* xp = x + (size_t)row * I_ + k0;
    float4 a = *reinterpret_cast<const float4*>(xp);
    float4 b = *reinterpret_cast<const float4*>(xp + 4);

    bf16x8 h;
    h[0] = (short)f2bf(a.x); h[1] = (short)f2bf(a.y);
    h[2] = (short)f2bf(a.z); h[3] = (short)f2bf(a.w);
    h[4] = (short)f2bf(b.x); h[5] = (short)f2bf(b.y);
    h[6] = (short)f2bf(b.z); h[7] = (short)f2bf(b.w);

    size_t off = (size_t)tt * XTILE + row * 128 + ((kl * 2) ^ ((row & 7) << 4));
    *reinterpret_cast<bf16x8*>(xb + off) = h;
}

// ---------------------------------------------------------------------------
// Prepass 2: w [2048 o][2048 k] f32 -> wp [512 grp][2048 k][4 o_local] bf16
// (8.4 MB). One block's 4 o's = one contiguous group -> GLDS16-only staging.
// Thread = (grp, k-pair): reads 4x float2 (coalesced per row), writes 16 B.
// ---------------------------------------------------------------------------
__global__ void wpack(const float* __restrict__ w, char* __restrict__ wp) {
    int idx = blockIdx.x * 256 + threadIdx.x;   // 0 .. 524287
    int grp = idx >> 10;                        // 0..511
    int kc2 = idx & 1023;                       // k-pair 0..1023

    bf16x8 h;
#pragma unroll
    for (int ol = 0; ol < 4; ++ol) {
        float2 v = *reinterpret_cast<const float2*>(
            w + ((size_t)(grp * 4 + ol)) * I_ + kc2 * 2);
        h[ol]     = (short)f2bf(v.x);
        h[4 + ol] = (short)f2bf(v.y);
    }
    *reinterpret_cast<bf16x8*>(wp + (size_t)grp * 16384 + kc2 * 16) = h;
}

// ---------------------------------------------------------------------------
// Main kernel: grid 512 x 256 thr (4 waves), 2 blocks/CU. Wave owns one o,
// full K, BK=64. Identical LDS-read/MFMA/barrier structure to R3; VMEM op
// count cut 2560 -> ~1700/CU: D staged in 5120-B supersteps (5 x GLDS16,
// no GLDS4), w from packed bf16 (2 x GLDS16 per 4 steps per block).
// Per wave-step avg ops: x 4 + D 2.5 + w 0.125 = 6.6.
// ---------------------------------------------------------------------------
__global__ __launch_bounds__(256, 2) void neuro_fused(
    const char*  __restrict__ xb,     // swizzled bf16 x tiles
    const char*  __restrict__ wp,     // packed bf16 w
    const float* __restrict__ ctx,    // [O_]
    const float* __restrict__ bias,   // [O_]
    const float* __restrict__ astro,  // [O_]
    const float* __restrict__ D,      // [O_, I_, SEG]
    float* __restrict__ out)          // [B_, O_]
{
    __shared__ __align__(16) char xs[2][XTILE];     // 32 KiB, x double buffer
    __shared__ __align__(16) char dD[4][2][DSS];    // 40 KiB, per-wave D dbuf
    __shared__ __align__(16) char wb[2][2048];      // 4 KiB, block w dbuf

    const int tid  = threadIdx.x;
    const int wave = tid >> 6;
    const int lane = tid & 63;
    const int o    = blockIdx.x * 4 + wave;
    const int col  = lane & 15;   // MFMA n-index
    const int g    = lane >> 4;   // k-group

    f32x4 acc[8];
#pragma unroll
    for (int m = 0; m < 8; ++m) acc[m] = (f32x4){0.f, 0.f, 0.f, 0.f};

    float am = astro[o] * ctx[o];
    am = 1.0f / (1.0f + __expf(-am));
    const float bo = bias[o];

    const char* Dbase = (const char*)D + (size_t)o * (I_ * SEG * 4);
    const int sw = (col & 7) << 4;

    // 4 GLDS16: wave stages rows [wave*32, +32) of tile t
    auto stage_x = [&](int t) {
        const char* src = xb + (size_t)t * XTILE + wave * 4096 + lane * 16;
        char* dst = &xs[t & 1][wave * 4096];
#pragma unroll
        for (int c = 0; c < 4; ++c)
            GLDS16(src + c * 1024, dst + c * 1024);
    };

    // 5 GLDS16: D superstep S (128 k x 10 j), contiguous 5120 B
    auto stage_D = [&](int S) {
        const char* src = Dbase + (size_t)S * DSS + lane * 16;
        char* dst = &dD[wave][S & 1][0];
#pragma unroll
        for (int c = 0; c < 5; ++c)
            GLDS16(src + c * 1024, dst + c * 1024);
    };

    // 2 GLDS16 by one wave: packed w for steps [g4*4, g4*4+4)
    auto stage_w = [&](int g4) {
        if (wave == (g4 & 3)) {
            const char* src = wp + (size_t)blockIdx.x * 16384 + g4 * 2048 + lane * 16;
            char* dst = &wb[g4 & 1][0];
            GLDS16(src, dst);
            GLDS16(src + 1024, dst + 1024);
        }
    };

    auto compute = [&](int t) {
        const char* xbase = &xs[t & 1][0];
        const char* dbase = &dD[wave][(t >> 1) & 1][(t & 1) * 2560];
        const char* wbase = &wb[(t >> 2) & 1][0];
#pragma unroll
        for (int kk = 0; kk < 2; ++kk) {
            bf16x8 bfrag;
            if (col < 10) {
                const char* fp = dbase + kk * 1280 + (8 * g) * 40 + col * 4;
#pragma unroll
                for (int e = 0; e < 8; ++e)
                    bfrag[e] = (short)f2bf(*reinterpret_cast<const float*>(fp + e * 40));
            } else if (col == 10) {
                const char* fp = wbase + ((t & 3) * 64 + kk * 32 + 8 * g) * 8 + wave * 2;
#pragma unroll
                for (int e = 0; e < 8; ++e)
                    bfrag[e] = *reinterpret_cast<const short*>(fp + e * 8);
            } else {
#pragma unroll
                for (int e = 0; e < 8; ++e) bfrag[e] = 0;
            }
            const int kswz = (kk * 64 + 16 * g) ^ sw;
#pragma unroll
            for (int m = 0; m < 8; ++m) {
                bf16x8 af = *reinterpret_cast<const bf16x8*>(
                    xbase + (m * 16 + col) * 128 + kswz);
                acc[m] = __builtin_amdgcn_mfma_f32_16x16x32_bf16(af, bfrag, acc[m], 0, 0, 0);
            }
        }
    };

    // prologue
    stage_x(0); stage_x(1);
    stage_D(0); stage_D(1);
    stage_w(0); stage_w(1);

#pragma unroll 1
    for (int t = 0; t < NT; ++t) {
        __syncthreads();                 // drain: everything staged so far is in LDS
        compute(t);
        __syncthreads();                 // all waves done reading replaced buffers
        if (t + 2 < NT) stage_x(t + 2);
        if ((t & 1) == 1) {
            int S = t >> 1;
            if (S + 2 < NSS) stage_D(S + 2);
        }
        if ((t & 3) == 3) {
            int g4 = t >> 2;
            if (g4 + 2 < 8) stage_w(g4 + 2);
        }
    }

    // --- epilogue: lane holds C[b = m*16 + g*4 + r][col] ---------------------
#pragma unroll
    for (int m = 0; m < 8; ++m) {
#pragma unroll
        for (int r = 0; r < 4; ++r) {
            float v = acc[m][r];
            float dend = (col < 10) ? fmaxf(v, 0.0f) : 0.0f;
#pragma unroll
            for (int sh = 1; sh < 16; sh <<= 1)
                dend += __shfl_xor(dend, sh, 64);
            float lin = __shfl(v, (lane & 48) | 10, 64);
            if (col == 0) {
                int b = m * 16 + g * 4 + r;
                out[(size_t)b * O_ + o] = dend + am * lin + bo;
            }
        }
    }
}

extern "C" void kernel_launch(void* const* d_in, const int* in_sizes, int n_in,
                              void* d_out, int out_size, void* d_ws, size_t ws_size,
                              hipStream_t stream) {
    const float* x     = (const float*)d_in[0];
    const float* ctx   = (const float*)d_in[1];
    // d_in[2] = prev_activation (unused by the reference output)
    const float* w     = (const float*)d_in[3];
    const float* bias  = (const float*)d_in[4];
    const float* astro = (const float*)d_in[5];
    const float* D     = (const float*)d_in[6];
    float* out = (float*)d_out;

    char* xb = (char*)d_ws;                 // 512 KiB swizzled bf16 x
    char* wpk = (char*)d_ws + 524288;       // 8.4 MiB packed bf16 w

    xconv<<<dim3(128), dim3(256), 0, stream>>>(x, xb);
    wpack<<<dim3(2048), dim3(256), 0, stream>>>(w, wpk);
    neuro_fused<<<dim3(512), dim3(256), 0, stream>>>(xb, wpk, ctx, bias, astro, D, out);
}

// Round 10
// 51.141 us; speedup vs baseline: 1.3687x; 1.2430x over previous
//
#include <hip/hip_runtime.h>
#include <hip/hip_bf16.h>

#define B_ 128
#define I_ 2048
#define O_ 2048
#define SEG 10
#define BK 64
#define NST (I_ / BK)      // 32 k-steps
#define XTILE 16384        // x tile: 128 rows x 64 k x 2B bf16, swizzled
#define DCH 2560           // D chunk: 64 i x 10 j x 4B f32, contiguous in D
#define DLS 2816           // + 256 B w chunk

typedef __attribute__((ext_vector_type(8))) short bf16x8;
typedef __attribute__((ext_vector_type(4))) float f32x4;

static __device__ __forceinline__ unsigned short f2bf(float f) {
    unsigned u = __float_as_uint(f);
    u += 0x7FFFu + ((u >> 16) & 1u);
    return (unsigned short)(u >> 16);
}

// v_cvt_pk_bf16_f32: two f32 -> packed 2xbf16 in one instruction (RNE)
static __device__ __forceinline__ unsigned cvt2(float lo, float hi) {
    __hip_bfloat162 h = __float22bfloat162_rn(make_float2(lo, hi));
    return *reinterpret_cast<unsigned*>(&h);
}

#define GLDS16(SRC, DST) \
    __builtin_amdgcn_global_load_lds( \
        (const __attribute__((address_space(1))) unsigned*)(SRC), \
        (__attribute__((address_space(3))) unsigned*)(DST), 16, 0, 0)
#define GLDS4(SRC, DST) \
    __builtin_amdgcn_global_load_lds( \
        (const __attribute__((address_space(1))) unsigned*)(SRC), \
        (__attribute__((address_space(3))) unsigned*)(DST), 4, 0, 0)

// ---------------------------------------------------------------------------
// Prepass: x [128][2048] f32 -> xb: 32 tiles of [128 rows][64 k] bf16.
// Row stride 128 B; XOR swizzle: byte(row,kl) = row*128 + ((kl*2)^((row&7)<<4))
// ---------------------------------------------------------------------------
__global__ void xconv(const float* __restrict__ x, char* __restrict__ xb) {
    int idx = blockIdx.x * 256 + threadIdx.x;   // one 8-k chunk each
    int row = idx >> 8;
    int c   = idx & 255;
    int k0  = c * 8;
    int tt  = k0 >> 6;                          // tile 0..31
    int kl  = k0 & 63;

    const float* xp = x + (size_t)row * I_ + k0;
    float4 a = *reinterpret_cast<const float4*>(xp);
    float4 b = *reinterpret_cast<const float4*>(xp + 4);

    bf16x8 h;
    h[0] = (short)f2bf(a.x); h[1] = (short)f2bf(a.y);
    h[2] = (short)f2bf(a.z); h[3] = (short)f2bf(a.w);
    h[4] = (short)f2bf(b.x); h[5] = (short)f2bf(b.y);
    h[6] = (short)f2bf(b.z); h[7] = (short)f2bf(b.w);

    size_t off = (size_t)tt * XTILE + row * 128 + ((kl * 2) ^ ((row & 7) << 4));
    *reinterpret_cast<bf16x8*>(xb + off) = h;
}

// ---------------------------------------------------------------------------
// Main fused kernel (R3 skeleton): grid 512, 4 waves/block, one o per wave,
// BK=64, x + D/w double-buffered via global_load_lds, 2 barriers per step.
// R10 change: compute() batches all LDS reads first, converts the D floats
// with v_cvt_pk_bf16_f32 (1 instr / 2 elems instead of ~9), then MFMAs —
// no sched_barriers, so the compiler can overlap read/cvt/MFMA via lgkmcnt.
// ---------------------------------------------------------------------------
__global__ __launch_bounds__(256, 2) void neuro_fused(
    const char*  __restrict__ xb,     // swizzled bf16 x tiles
    const float* __restrict__ ctx,    // [O_]
    const float* __restrict__ w,      // [O_, I_]
    const float* __restrict__ bias,   // [O_]
    const float* __restrict__ astro,  // [O_]
    const float* __restrict__ D,      // [O_, I_, SEG]
    float* __restrict__ out)          // [B_, O_]
{
    __shared__ __align__(16) char xs[2][XTILE];     // 32 KiB
    __shared__ __align__(16) char dls[4][2][DLS];   // 22 KiB

    const int tid  = threadIdx.x;
    const int wave = tid >> 6;
    const int lane = tid & 63;
    const int o    = blockIdx.x * 4 + wave;
    const int col  = lane & 15;   // MFMA n-index
    const int g    = lane >> 4;   // k-group

    f32x4 acc[8];
#pragma unroll
    for (int m = 0; m < 8; ++m) acc[m] = (f32x4){0.f, 0.f, 0.f, 0.f};

    float am = astro[o] * ctx[o];
    am = 1.0f / (1.0f + __expf(-am));
    const float bo = bias[o];

    // per-lane B-fragment addressing within the staged chunk:
    // cols 0..9 dendrite (stride 40 B), cols 10..15 weight row (stride 4 B;
    // cols 11..15 compute the same finite dot as col 10, epilogue ignores them)
    const int fbase = (col < 10) ? col * 4 : DCH;
    const int fstr  = (col < 10) ? 40 : 4;
    const int sw    = (col & 7) << 4;

    auto stage_x = [&](int t, int buf) {
        const char* src = xb + (size_t)t * XTILE + wave * 4096 + lane * 16;
        char* dst = &xs[buf][wave * 4096];
#pragma unroll
        for (int c = 0; c < 4; ++c)
            GLDS16(src + c * 1024, dst + c * 1024);
    };

    auto stage_d = [&](int t, int buf) {
        const char* srcD = (const char*)D + (size_t)o * (I_ * SEG * 4) + (size_t)t * DCH;
        char* dst = &dls[wave][buf][0];
#pragma unroll
        for (int c = 0; c < 2; ++c)
            GLDS16(srcD + c * 1024 + lane * 16, dst + c * 1024);
#pragma unroll
        for (int c = 0; c < 2; ++c)
            GLDS4(srcD + 2048 + c * 256 + lane * 4, dst + 2048 + c * 256);
        const char* srcW = (const char*)w + (size_t)o * (I_ * 4) + t * (BK * 4);
        GLDS4(srcW + lane * 4, dst + DCH);
    };

    auto compute = [&](int buf) {
        const char* xbase = &xs[buf][0];
        const char* dbase = &dls[wave][buf][0];

        // phase 1: issue ALL fragment loads (16 b128 + 16 b32)
        bf16x8 af[2][8];
#pragma unroll
        for (int kk = 0; kk < 2; ++kk) {
            const int kswz = (64 * kk + 16 * g) ^ sw;
#pragma unroll
            for (int m = 0; m < 8; ++m)
                af[kk][m] = *reinterpret_cast<const bf16x8*>(
                    xbase + (m * 16 + col) * 128 + kswz);
        }
        float bv[2][8];
#pragma unroll
        for (int kk = 0; kk < 2; ++kk) {
            const char* fp = dbase + fbase + (32 * kk + 8 * g) * fstr;
#pragma unroll
            for (int e = 0; e < 8; ++e)
                bv[kk][e] = *reinterpret_cast<const float*>(fp + e * fstr);
        }

        // phase 2: pack B via v_cvt_pk_bf16_f32; phase 3: MFMA
#pragma unroll
        for (int kk = 0; kk < 2; ++kk) {
            union { bf16x8 v; unsigned u[4]; } bf;
#pragma unroll
            for (int e2 = 0; e2 < 4; ++e2)
                bf.u[e2] = cvt2(bv[kk][2 * e2], bv[kk][2 * e2 + 1]);
#pragma unroll
            for (int m = 0; m < 8; ++m)
                acc[m] = __builtin_amdgcn_mfma_f32_16x16x32_bf16(af[kk][m], bf.v, acc[m], 0, 0, 0);
        }
    };

    stage_x(0, 0);
    stage_d(0, 0);
    __syncthreads();   // vmcnt(0) drain -> buf0 ready

#pragma unroll 1
    for (int t = 0; t < NST; t += 2) {
        stage_x(t + 1, 1);
        stage_d(t + 1, 1);
        compute(0);
        __syncthreads();

        if (t + 2 < NST) {
            stage_x(t + 2, 0);
            stage_d(t + 2, 0);
        }
        compute(1);
        __syncthreads();
    }

    // --- epilogue: lane holds C[b = m*16 + g*4 + r][col] ---------------------
#pragma unroll
    for (int m = 0; m < 8; ++m) {
#pragma unroll
        for (int r = 0; r < 4; ++r) {
            float v = acc[m][r];
            float dend = (col < 10) ? fmaxf(v, 0.0f) : 0.0f;
#pragma unroll
            for (int s = 1; s < 16; s <<= 1)
                dend += __shfl_xor(dend, s, 64);
            float lin = __shfl(v, (lane & 48) | 10, 64);
            if (col == 0) {
                int b = m * 16 + g * 4 + r;
                out[(size_t)b * O_ + o] = dend + am * lin + bo;
            }
        }
    }
}

extern "C" void kernel_launch(void* const* d_in, const int* in_sizes, int n_in,
                              void* d_out, int out_size, void* d_ws, size_t ws_size,
                              hipStream_t stream) {
    const float* x     = (const float*)d_in[0];
    const float* ctx   = (const float*)d_in[1];
    // d_in[2] = prev_activation (unused by the reference output)
    const float* w     = (const float*)d_in[3];
    const float* bias  = (const float*)d_in[4];
    const float* astro = (const float*)d_in[5];
    const float* D     = (const float*)d_in[6];
    float* out = (float*)d_out;
    char* xb = (char*)d_ws;   // 512 KiB swizzled bf16 x

    xconv<<<dim3(128), dim3(256), 0, stream>>>(x, xb);
    neuro_fused<<<dim3(512), dim3(256), 0, stream>>>(xb, ctx, w, bias, astro, D, out);
}